// Round 5
// baseline (237.530 us; speedup 1.0000x reference)
//
#include <hip/hip_runtime.h>
#include <hip/hip_bf16.h>

// LengthRegulator, round 5: two-kernel split.
//   k_index  (32 blocks): per-row cumsum + SCATTER frame->phoneme table (no
//            binary search), idx[B][TOUT] in d_ws. -1 marks pad frames.
//   k_stream (2048 blocks): memcpy-shaped expansion. Static trip count (16,
//            fully unrolled), no LDS, no barriers, 1 cached idx load + 1
//            gather + 1 nontemporal 16B store per iteration.
// Roofline: 192 MiB write + ~25 MiB read -> ~36 us at 6.3 TB/s. Harness
// reset floor (768 MiB ws poison + 192 MiB out poison + input restore) is
// ~165 us of the measured total.

#define B    32
#define T    512
#define D    384
#define TOUT 4096           // T * DUR_MAX
#define CH   (D / 4)        // 96 float4 chunks per frame
#define F    64             // frames per k_stream block
#define NT2  384            // k_stream threads: 4 frame-lanes x 96 chunks

typedef float f4 __attribute__((ext_vector_type(4)));

// ---------- kernel 1: per-row scan + scatter frame->phoneme table ----------
__global__ __launch_bounds__(T) void k_index(const int* __restrict__ dur,
                                             int* __restrict__ idx) {
    __shared__ int s_idx[TOUT];     // 16 KB frame->phoneme table
    __shared__ int s_wsum[T / 64];
    const int b = blockIdx.x, tid = threadIdx.x;
    const int lane = tid & 63, w = tid >> 6;

    int d = dur[b * T + tid];
    // inclusive scan: shfl within wave, LDS combine across 8 waves
    int sum = d;
    #pragma unroll
    for (int off = 1; off < 64; off <<= 1) {
        int v = __shfl_up(sum, off);
        if (lane >= off) sum += v;
    }
    if (lane == 63) s_wsum[w] = sum;
    __syncthreads();
    int prefix = 0, rowtot = 0;
    #pragma unroll
    for (int i = 0; i < T / 64; ++i) {
        int v = s_wsum[i];
        rowtot += v;
        if (i < w) prefix += v;
    }
    int cum = sum + prefix;         // inclusive frame offset

    // torch edge case: row total == 0 -> if GLOBAL total == 0, all d become 1
    if (rowtot == 0) {              // block-uniform branch, rare
        int g = 0;
        for (int i = tid; i < B * T; i += T) g += dur[i];
        #pragma unroll
        for (int o = 32; o > 0; o >>= 1) g += __shfl_down(g, o);
        __syncthreads();            // s_wsum reuse
        if (lane == 0) s_wsum[w] = g;
        __syncthreads();
        int tot = 0;
        #pragma unroll
        for (int i = 0; i < T / 64; ++i) tot += s_wsum[i];
        if (tot == 0) { d = 1; cum = tid + 1; }
    }

    // init table to pad, then scatter: phoneme tid owns frames [cum-d, cum)
    for (int i = tid; i < TOUT; i += T) s_idx[i] = -1;
    __syncthreads();
    for (int k = cum - d; k < cum; ++k) s_idx[k] = tid;
    __syncthreads();
    for (int i = tid; i < TOUT; i += T) idx[b * TOUT + i] = s_idx[i];
}

// ---------- kernel 2: pure streaming expansion ----------
// grid = (TOUT/F, B), block = 384. Thread t -> frame-lane t/96, chunk t%96.
__global__ __launch_bounds__(NT2) void k_stream(const f4* __restrict__ xs4,
                                                const int* __restrict__ idx,
                                                f4* __restrict__ out4) {
    const int b      = blockIdx.y;
    const int frame0 = blockIdx.x * F;
    const int t      = threadIdx.x;
    const int fl0    = t / CH;          // 0..3
    const int c      = t - fl0 * CH;    // 0..95
    const size_t obase = ((size_t)b * TOUT + frame0) * CH;
    const size_t ibase = (size_t)b * T * CH;
    const int* idxrow = idx + b * TOUT + frame0;

    #pragma unroll
    for (int k = 0; k < F / 4; ++k) {   // 16 iterations, fully unrolled
        int f = fl0 + 4 * k;
        int j = idxrow[f];              // L1-hot, <=2 distinct addrs per wave
        f4 v = (f4){0.f, 0.f, 0.f, 0.f};
        if (j >= 0) v = xs4[ibase + (size_t)j * CH + c];
        __builtin_nontemporal_store(v, out4 + obase + (size_t)f * CH + c);
    }
}

extern "C" void kernel_launch(void* const* d_in, const int* in_sizes, int n_in,
                              void* d_out, int out_size, void* d_ws, size_t ws_size,
                              hipStream_t stream) {
    const float* xs  = (const float*)d_in[0];
    const int*   dur = (const int*)d_in[1];
    float*       out = (float*)d_out;
    int*         idx = (int*)d_ws;      // B*TOUT ints = 512 KB

    k_index<<<B, T, 0, stream>>>(dur, idx);
    dim3 grid(TOUT / F, B);             // 64 x 32 = 2048 blocks
    k_stream<<<grid, NT2, 0, stream>>>((const f4*)xs, idx, (f4*)out);
}

// Round 6
// 227.938 us; speedup vs baseline: 1.0421x; 1.0421x over previous
//
#include <hip/hip_runtime.h>
#include <hip/hip_bf16.h>

// LengthRegulator, round 6: single fused kernel.
//   - scatter-built per-window frame->phoneme table in LDS (no binary search)
//   - fully-pad blocks (frame0 >= row total) take a fill-identical pure-store
//     path: no LDS reads, no gathers, no exec-mask ops (~56% of output)
//   - REGULAR stores (R4/R5's nontemporal stores never beat R2's plain ones;
//     the 6.3 TB/s harness fill uses plain stores)
//   - static 24-iteration fully-unrolled body, incremental f/c (no div)
// Roofline: 192 MiB write + ~25 MiB read -> ~36 us at 6.3 TB/s. Harness
// reset floor (768 MiB ws poison + 192 MiB out poison + restore) ~173 us.

#define B    32
#define T    512
#define D    384
#define TOUT 4096           // T * DUR_MAX
#define CH   (D / 4)        // 96 float4 chunks per frame
#define F    128            // output frames per block
#define NT   512            // threads per block
#define ITEMS (F * CH)      // 12288 float4 per block
#define ITER (ITEMS / NT)   // 24

typedef float f4 __attribute__((ext_vector_type(4)));

__global__ __launch_bounds__(NT) void k_lenreg(const f4* __restrict__ xs4,
                                               const int* __restrict__ dur,
                                               f4* __restrict__ out4) {
    __shared__ int s_idx[F];        // frame->phoneme for this window, -1 = pad
    __shared__ int s_wsum[NT / 64];
    const int b      = blockIdx.y;
    const int frame0 = blockIdx.x * F;
    const int tid    = threadIdx.x;
    const int lane   = tid & 63;
    const int w      = tid >> 6;

    // ---- inclusive scan of this row's durations: shfl in wave, LDS combine ----
    int d = dur[b * T + tid];
    int sum = d;
    #pragma unroll
    for (int off = 1; off < 64; off <<= 1) {
        int v = __shfl_up(sum, off);
        if (lane >= off) sum += v;
    }
    if (lane == 63) s_wsum[w] = sum;
    __syncthreads();
    int prefix = 0, rowtot = 0;
    #pragma unroll
    for (int i = 0; i < NT / 64; ++i) {
        int v = s_wsum[i];
        rowtot += v;
        if (i < w) prefix += v;
    }
    int cum = sum + prefix;         // inclusive frame offset of phoneme tid

    // ---- torch edge case: row total 0 -> if GLOBAL total 0, all d become 1 ----
    if (rowtot == 0) {              // block-uniform, rare
        int g = 0;
        for (int i = tid; i < B * T; i += NT) g += dur[i];
        #pragma unroll
        for (int o = 32; o > 0; o >>= 1) g += __shfl_down(g, o);
        __syncthreads();
        if (lane == 0) s_wsum[w] = g;
        __syncthreads();
        int tot = 0;
        #pragma unroll
        for (int i = 0; i < NT / 64; ++i) tot += s_wsum[i];
        if (tot == 0) { d = 1; cum = tid + 1; rowtot = T; }
    }

    const size_t obase = ((size_t)b * TOUT + frame0) * CH;

    // ---- fully-pad window: fill-identical pure-store loop ----
    if (frame0 >= rowtot) {         // block-uniform
        const f4 z = (f4){0.f, 0.f, 0.f, 0.f};
        #pragma unroll
        for (int k = 0; k < ITER; ++k)
            out4[obase + tid + k * NT] = z;
        return;
    }

    // ---- scatter: phoneme tid owns frames [cum-d, cum) ∩ window ----
    if (tid < F) s_idx[tid] = -1;
    __syncthreads();
    {
        int a = cum - d, e = cum;
        if (a < frame0) a = frame0;
        int hi = frame0 + F;
        if (e > hi) e = hi;
        for (int k = a; k < e; ++k) s_idx[k - frame0] = tid;
    }
    __syncthreads();

    // ---- copy: static trip count, contiguous stores, incremental f/c ----
    const size_t ibase = (size_t)b * T * CH;
    int f = tid / CH;               // 0..5 (one div, outside loop)
    int c = tid - f * CH;
    #pragma unroll
    for (int k = 0; k < ITER; ++k) {
        int j = s_idx[f];           // <=2 distinct LDS addrs per wave
        f4 v = (f4){0.f, 0.f, 0.f, 0.f};
        if (j >= 0) v = xs4[ibase + (size_t)j * CH + c];
        out4[obase + tid + k * NT] = v;
        f += NT / CH;               // 512 = 5*96 + 32
        c += NT - (NT / CH) * CH;
        if (c >= CH) { c -= CH; ++f; }   // cndmask under unrolling
    }
}

extern "C" void kernel_launch(void* const* d_in, const int* in_sizes, int n_in,
                              void* d_out, int out_size, void* d_ws, size_t ws_size,
                              hipStream_t stream) {
    const float* xs  = (const float*)d_in[0];
    const int*   dur = (const int*)d_in[1];
    float*       out = (float*)d_out;

    dim3 grid(TOUT / F, B);         // 32 x 32 = 1024 blocks
    k_lenreg<<<grid, NT, 0, stream>>>((const f4*)xs, dur, (f4*)out);
}